// Round 2
// baseline (198.137 us; speedup 1.0000x reference)
//
#include <hip/hip_runtime.h>
#include <math.h>

// PointLoss: fused masked reduction over B*H*W pixels -> scalar.
// R1: 4 pixels/thread, float4/int4 coalesced up-front loads, exact grid fit
// (2396160 = 2340 blocks * 256 threads * 4 px), no grid-stride loop.

namespace {
constexpr int B_ = 64, H_ = 52, W_ = 720;
constexpr int HW_ = H_ * W_;            // 37440
constexpr int NPIX = B_ * HW_;          // 2396160
constexpr int NTHREADS = 256;
constexpr int PXT = 4;                  // pixels per thread
constexpr int NBLOCKS = NPIX / (NTHREADS * PXT);  // 2340 exactly
constexpr float EPSF = 1e-8f;
constexpr float RAD2DEG = 57.29577951308232f;   // 180/pi
}

__global__ __launch_bounds__(NTHREADS) void pointloss_main(
    const float* __restrict__ v,      // vertexmap_proj   [B,H,W,3]
    const float* __restrict__ nrm,    // normalmap_proj   [B,H,W,3]
    const float* __restrict__ unc,    // uncertainty      [B,H,W]
    const float* __restrict__ nown,   // now_normalmap    [B,H,W,3]
    const float* __restrict__ conf,   // now_confidencemap[B,H,W]
    const float* __restrict__ lastn,  // last_normalmap   [B,H,W,3]
    const float* __restrict__ lastv,  // last_vertexmap   [B,H,W,3]
    const int*   __restrict__ nowm,   // now_maskmap      [B,H,W]
    const int*   __restrict__ lastm,  // last_maskmap     [B,H,W]
    float* __restrict__ partials)     // [NBLOCKS*5]
{
    const int t  = blockIdx.x * NTHREADS + threadIdx.x;
    const int p0 = t * PXT;

    // ---- up-front coalesced vector loads (issued before any compute) ----
    const float4* v4 = (const float4*)(v + 3 * p0);
    const float4 va = v4[0], vb = v4[1], vc = v4[2];
    const float4* n4 = (const float4*)(nown + 3 * p0);
    const float4 na = n4[0], nb = n4[1], nc = n4[2];
    const int4   mm = *(const int4*)(nowm + p0);
    const float4 cf = *(const float4*)(conf + p0);
    const float4 uu = *(const float4*)(unc + p0);

    // unpack AoS [.,3] from the three float4s
    const float vx[PXT] = {va.x, va.w, vb.z, vc.y};
    const float vy[PXT] = {va.y, vb.x, vb.w, vc.z};
    const float vz[PXT] = {va.z, vb.y, vc.x, vc.w};
    const float ax[PXT] = {na.x, na.w, nb.z, nc.y};
    const float ay[PXT] = {na.y, nb.x, nb.w, nc.z};
    const float az[PXT] = {na.z, nb.y, nc.x, nc.w};
    const int   mi[PXT] = {mm.x, mm.y, mm.z, mm.w};
    const float cfa[PXT] = {cf.x, cf.y, cf.z, cf.w};
    const float ua[PXT]  = {uu.x, uu.y, uu.z, uu.w};

    float s_m0 = 0.f, s_fov = 0.f, s_m = 0.f, s_icp = 0.f, s_ang = 0.f;

    // 4 independent chains -> ILP for the transcendentals
    float pxx[PXT], pyy[PXT];
    bool  m0[PXT];
    #pragma unroll
    for (int j = 0; j < PXT; ++j) {
        m0[j] = (mi[j] > 0) &&
                ((fabsf(ax[j]) + fabsf(ay[j]) + fabsf(az[j])) != 0.0f);
        const float d2 = vx[j]*vx[j] + vy[j]*vy[j] + vz[j]*vz[j] + EPSF;
        const float q  = fminf(fmaxf(vz[j] * rsqrtf(d2), -1.f), 1.f);
        const float yaw   = atan2f(vy[j], vx[j]) * RAD2DEG;
        const float pitch = asinf(q) * RAD2DEG;
        pxx[j] = (180.0f - yaw) * 2.0f;
        pyy[j] = (3.0f - pitch) * 2.0f;
    }

    #pragma unroll
    for (int j = 0; j < PXT; ++j) {
        const float px = pxx[j], py = pyy[j];
        if (m0[j]) {
            const float dx = px - fminf(fmaxf(px, 0.f), (float)(W_ - 1));
            const float dy = py - fminf(fmaxf(py, 0.f), (float)(H_ - 1));
            s_m0 += 1.0f;
            s_fov += dx*dx + dy*dy;
        }
        const float prx = rintf(px), pry = rintf(py);  // round-half-even
        const bool inb = (prx >= 0.f) && (prx < (float)W_) &&
                         (pry >= 0.f) && (pry < (float)H_);
        if (m0[j] && inb && (cfa[j] >= 0.5f)) {
            const int p  = p0 + j;
            const int gi = (p / HW_) * HW_ + (int)pry * W_ + (int)prx;
            const float lx = lastn[3*gi+0], ly = lastn[3*gi+1], lz = lastn[3*gi+2];
            if ((lastm[gi] > 0) && ((fabsf(lx) + fabsf(ly) + fabsf(lz)) != 0.f)) {
                const float wx = lastv[3*gi+0], wy = lastv[3*gi+1], wz = lastv[3*gi+2];
                const float r  = lx*(vx[j]-wx) + ly*(vy[j]-wy) + lz*(vz[j]-wz);
                const float nx = nrm[3*p+0], ny = nrm[3*p+1], nz = nrm[3*p+2];
                const float dt = lx*nx + ly*ny + lz*nz;
                const float den = (lx*lx + ly*ly + lz*lz) *
                                  (nx*nx + ny*ny + nz*nz) + EPSF;
                const float cosang = fabsf(dt) * rsqrtf(den);
                s_m   += 1.0f;
                s_icp += ua[j] * fabsf(r);
                s_ang += ua[j] * (1.0f - cosang);
            }
        }
    }

    // wave64 shuffle reduce
    #pragma unroll
    for (int off = 32; off > 0; off >>= 1) {
        s_m0  += __shfl_down(s_m0,  off);
        s_fov += __shfl_down(s_fov, off);
        s_m   += __shfl_down(s_m,   off);
        s_icp += __shfl_down(s_icp, off);
        s_ang += __shfl_down(s_ang, off);
    }
    __shared__ float red[NTHREADS / 64][5];
    const int lane = threadIdx.x & 63;
    const int wv   = threadIdx.x >> 6;
    if (lane == 0) {
        red[wv][0] = s_m0;  red[wv][1] = s_fov; red[wv][2] = s_m;
        red[wv][3] = s_icp; red[wv][4] = s_ang;
    }
    __syncthreads();
    if (threadIdx.x == 0) {
        float tt[5] = {0.f, 0.f, 0.f, 0.f, 0.f};
        for (int w2 = 0; w2 < NTHREADS / 64; ++w2)
            for (int c = 0; c < 5; ++c) tt[c] += red[w2][c];
        float* o = partials + blockIdx.x * 5;
        for (int c = 0; c < 5; ++c) o[c] = tt[c];
    }
}

__global__ __launch_bounds__(256) void pointloss_finalize(
    const float* __restrict__ partials,
    const float* __restrict__ sx,
    const float* __restrict__ sq,
    float* __restrict__ out)
{
    double a0 = 0, a1 = 0, a2 = 0, a3 = 0, a4 = 0;
    for (int i = threadIdx.x; i < NBLOCKS; i += 256) {
        const float* pp = partials + i * 5;
        a0 += (double)pp[0]; a1 += (double)pp[1]; a2 += (double)pp[2];
        a3 += (double)pp[3]; a4 += (double)pp[4];
    }
    #pragma unroll
    for (int off = 32; off > 0; off >>= 1) {
        a0 += __shfl_down(a0, off);
        a1 += __shfl_down(a1, off);
        a2 += __shfl_down(a2, off);
        a3 += __shfl_down(a3, off);
        a4 += __shfl_down(a4, off);
    }
    __shared__ double red[4][5];
    const int lane = threadIdx.x & 63;
    const int wv   = threadIdx.x >> 6;
    if (lane == 0) {
        red[wv][0] = a0; red[wv][1] = a1; red[wv][2] = a2;
        red[wv][3] = a3; red[wv][4] = a4;
    }
    __syncthreads();
    if (threadIdx.x == 0) {
        double t[5] = {0, 0, 0, 0, 0};
        for (int w2 = 0; w2 < 4; ++w2)
            for (int c = 0; c < 5; ++c) t[c] += red[w2][c];
        const double n0 = fmax(t[0], 1.0);
        const double n  = fmax(t[2], 1.0);
        const double sx0 = (double)sx[0], sq0 = (double)sq[0];
        const double total = exp(-sx0) * (t[3] / n) + sx0
                           + exp(-sq0) * (t[4] / n) + sq0
                           + t[1] / n0;   // LAMDA = 1, ANGRATE = 1
        out[0] = (float)total;
    }
}

extern "C" void kernel_launch(void* const* d_in, const int* in_sizes, int n_in,
                              void* d_out, int out_size, void* d_ws, size_t ws_size,
                              hipStream_t stream) {
    const float* v     = (const float*)d_in[0];
    const float* nrm   = (const float*)d_in[1];
    const float* unc   = (const float*)d_in[2];
    const float* nown  = (const float*)d_in[3];
    const float* conf  = (const float*)d_in[4];
    const float* lastn = (const float*)d_in[5];
    const float* lastv = (const float*)d_in[6];
    const float* sx    = (const float*)d_in[7];
    const float* sq    = (const float*)d_in[8];
    const int*   nowm  = (const int*)d_in[9];
    const int*   lastm = (const int*)d_in[10];

    float* partials = (float*)d_ws;  // NBLOCKS*5 floats ~ 47 KB

    pointloss_main<<<NBLOCKS, NTHREADS, 0, stream>>>(
        v, nrm, unc, nown, conf, lastn, lastv, nowm, lastm, partials);
    pointloss_finalize<<<1, 256, 0, stream>>>(partials, sx, sq, (float*)d_out);
}

// Round 3
// 194.545 us; speedup vs baseline: 1.0185x; 1.0185x over previous
//
#include <hip/hip_runtime.h>
#include <math.h>

// PointLoss: fused masked reduction over B*H*W pixels -> scalar.
// R2: 2048 blocks (exact 1.0 residency rounds: 8192 waves = 256 CU * 32),
// grid-stride with software-pipelined prefetch of next iteration's streaming
// loads (kept live in registers across the compute), and the gather chain
// flattened to ONE memory round-trip (lastn+lastm+lastv+nrm issued together).

namespace {
constexpr int B_ = 64, H_ = 52, W_ = 720;
constexpr int HW_ = H_ * W_;            // 37440
constexpr int NPIX = B_ * HW_;          // 2396160
constexpr int NTHREADS = 256;
constexpr int NBLOCKS = 2048;           // 8 blocks/CU * 256 CU, exact fit
constexpr int STRIDE = NBLOCKS * NTHREADS;   // 524288
constexpr int NITER = (NPIX + STRIDE - 1) / STRIDE;  // 5 (4 full + partial)
constexpr float EPSF = 1e-8f;
constexpr float RAD2DEG = 57.29577951308232f;   // 180/pi
}

__global__ __launch_bounds__(NTHREADS) void pointloss_main(
    const float* __restrict__ v,      // vertexmap_proj   [B,H,W,3]
    const float* __restrict__ nrm,    // normalmap_proj   [B,H,W,3]
    const float* __restrict__ unc,    // uncertainty      [B,H,W]
    const float* __restrict__ nown,   // now_normalmap    [B,H,W,3]
    const float* __restrict__ conf,   // now_confidencemap[B,H,W]
    const float* __restrict__ lastn,  // last_normalmap   [B,H,W,3]
    const float* __restrict__ lastv,  // last_vertexmap   [B,H,W,3]
    const int*   __restrict__ nowm,   // now_maskmap      [B,H,W]
    const int*   __restrict__ lastm,  // last_maskmap     [B,H,W]
    float* __restrict__ partials)     // [NBLOCKS*5]
{
    float s_m0 = 0.f, s_fov = 0.f, s_m = 0.f, s_icp = 0.f, s_ang = 0.f;

    int p = blockIdx.x * NTHREADS + threadIdx.x;   // always < NPIX (iter 0 valid)

    // ---- prologue: load iteration 0's streaming data ----
    float vx = v[3*p+0],  vy = v[3*p+1],  vz = v[3*p+2];
    float ax = nown[3*p+0], ay = nown[3*p+1], az = nown[3*p+2];
    int   mi = nowm[p];
    float cfv = conf[p];
    float uv  = unc[p];

    #pragma unroll
    for (int it = 0; it < NITER; ++it) {
        // ---- prefetch next iteration (issued before current compute) ----
        const int pn = p + STRIDE;
        const bool hasnext = (it + 1 < NITER) && (pn < NPIX);
        const int pl = hasnext ? pn : p;        // safe in-bounds address
        const float nvx = v[3*pl+0],  nvy = v[3*pl+1],  nvz = v[3*pl+2];
        const float nax = nown[3*pl+0], nay = nown[3*pl+1], naz = nown[3*pl+2];
        const int   nmi = nowm[pl];
        const float ncf = conf[pl];
        const float nuv = unc[pl];

        // ---- compute current pixel p ----
        const bool valid = (p < NPIX);
        const bool mask0 = valid && (mi > 0) &&
                           ((fabsf(ax) + fabsf(ay) + fabsf(az)) != 0.0f);

        const float d2 = vx*vx + vy*vy + vz*vz + EPSF;
        const float depth = sqrtf(d2);
        const float yaw   = atan2f(vy, vx) * RAD2DEG;
        const float q     = fminf(fmaxf(vz / depth, -1.f), 1.f);
        const float pitch = asinf(q) * RAD2DEG;
        const float px = (180.0f - yaw) * 2.0f;   // /DH, DH=0.5
        const float py = (3.0f - pitch) * 2.0f;   // /DV, DV=0.5

        if (mask0) {
            const float dx = px - fminf(fmaxf(px, 0.f), (float)(W_ - 1));
            const float dy = py - fminf(fmaxf(py, 0.f), (float)(H_ - 1));
            s_m0 += 1.0f;
            s_fov += dx*dx + dy*dy;
        }

        const float prx = rintf(px), pry = rintf(py);  // round-half-even
        const bool inb = (prx >= 0.f) && (prx < (float)W_) &&
                         (pry >= 0.f) && (pry < (float)H_);

        if (mask0 && inb && (cfv >= 0.5f)) {
            const int gi = (p / HW_) * HW_ + (int)pry * W_ + (int)prx;
            // issue ALL gather loads together -> one memory round-trip
            const float lx = lastn[3*gi+0], ly = lastn[3*gi+1], lz = lastn[3*gi+2];
            const int   lmv = lastm[gi];
            const float wx = lastv[3*gi+0], wy = lastv[3*gi+1], wz = lastv[3*gi+2];
            const float nx = nrm[3*p+0],   ny = nrm[3*p+1],   nz = nrm[3*p+2];
            if ((lmv > 0) && ((fabsf(lx) + fabsf(ly) + fabsf(lz)) != 0.f)) {
                const float r  = lx*(vx-wx) + ly*(vy-wy) + lz*(vz-wz);
                const float dt = lx*nx + ly*ny + lz*nz;
                const float den = (lx*lx + ly*ly + lz*lz) *
                                  (nx*nx + ny*ny + nz*nz) + EPSF;
                const float cosang = fabsf(dt) * rsqrtf(den);
                s_m   += 1.0f;
                s_icp += uv * fabsf(r);
                s_ang += uv * (1.0f - cosang);
            }
        }

        // ---- rotate pipeline registers ----
        vx = nvx; vy = nvy; vz = nvz;
        ax = nax; ay = nay; az = naz;
        mi = nmi; cfv = ncf; uv = nuv;
        p = pn;
    }

    // wave64 shuffle reduce
    #pragma unroll
    for (int off = 32; off > 0; off >>= 1) {
        s_m0  += __shfl_down(s_m0,  off);
        s_fov += __shfl_down(s_fov, off);
        s_m   += __shfl_down(s_m,   off);
        s_icp += __shfl_down(s_icp, off);
        s_ang += __shfl_down(s_ang, off);
    }
    __shared__ float red[NTHREADS / 64][5];
    const int lane = threadIdx.x & 63;
    const int wv   = threadIdx.x >> 6;
    if (lane == 0) {
        red[wv][0] = s_m0;  red[wv][1] = s_fov; red[wv][2] = s_m;
        red[wv][3] = s_icp; red[wv][4] = s_ang;
    }
    __syncthreads();
    if (threadIdx.x == 0) {
        float tt[5] = {0.f, 0.f, 0.f, 0.f, 0.f};
        for (int w2 = 0; w2 < NTHREADS / 64; ++w2)
            for (int c = 0; c < 5; ++c) tt[c] += red[w2][c];
        float* o = partials + blockIdx.x * 5;
        for (int c = 0; c < 5; ++c) o[c] = tt[c];
    }
}

__global__ __launch_bounds__(256) void pointloss_finalize(
    const float* __restrict__ partials,
    const float* __restrict__ sx,
    const float* __restrict__ sq,
    float* __restrict__ out)
{
    double a0 = 0, a1 = 0, a2 = 0, a3 = 0, a4 = 0;
    for (int i = threadIdx.x; i < NBLOCKS; i += 256) {
        const float* pp = partials + i * 5;
        a0 += (double)pp[0]; a1 += (double)pp[1]; a2 += (double)pp[2];
        a3 += (double)pp[3]; a4 += (double)pp[4];
    }
    #pragma unroll
    for (int off = 32; off > 0; off >>= 1) {
        a0 += __shfl_down(a0, off);
        a1 += __shfl_down(a1, off);
        a2 += __shfl_down(a2, off);
        a3 += __shfl_down(a3, off);
        a4 += __shfl_down(a4, off);
    }
    __shared__ double red[4][5];
    const int lane = threadIdx.x & 63;
    const int wv   = threadIdx.x >> 6;
    if (lane == 0) {
        red[wv][0] = a0; red[wv][1] = a1; red[wv][2] = a2;
        red[wv][3] = a3; red[wv][4] = a4;
    }
    __syncthreads();
    if (threadIdx.x == 0) {
        double t[5] = {0, 0, 0, 0, 0};
        for (int w2 = 0; w2 < 4; ++w2)
            for (int c = 0; c < 5; ++c) t[c] += red[w2][c];
        const double n0 = fmax(t[0], 1.0);
        const double n  = fmax(t[2], 1.0);
        const double sx0 = (double)sx[0], sq0 = (double)sq[0];
        const double total = exp(-sx0) * (t[3] / n) + sx0
                           + exp(-sq0) * (t[4] / n) + sq0
                           + t[1] / n0;   // LAMDA = 1, ANGRATE = 1
        out[0] = (float)total;
    }
}

extern "C" void kernel_launch(void* const* d_in, const int* in_sizes, int n_in,
                              void* d_out, int out_size, void* d_ws, size_t ws_size,
                              hipStream_t stream) {
    const float* v     = (const float*)d_in[0];
    const float* nrm   = (const float*)d_in[1];
    const float* unc   = (const float*)d_in[2];
    const float* nown  = (const float*)d_in[3];
    const float* conf  = (const float*)d_in[4];
    const float* lastn = (const float*)d_in[5];
    const float* lastv = (const float*)d_in[6];
    const float* sx    = (const float*)d_in[7];
    const float* sq    = (const float*)d_in[8];
    const int*   nowm  = (const int*)d_in[9];
    const int*   lastm = (const int*)d_in[10];

    float* partials = (float*)d_ws;  // NBLOCKS*5 floats = 40 KB

    pointloss_main<<<NBLOCKS, NTHREADS, 0, stream>>>(
        v, nrm, unc, nown, conf, lastn, lastv, nowm, lastm, partials);
    pointloss_finalize<<<1, 256, 0, stream>>>(partials, sx, sq, (float*)d_out);
}